// Round 5
// baseline (10003.126 us; speedup 1.0000x reference)
//
#include <hip/hip_runtime.h>
#include <hip/hip_bf16.h>
#include <math.h>

typedef __bf16 bf16_t;
typedef __bf16 bf16x4 __attribute__((ext_vector_type(4)));
typedef __bf16 bf16x8 __attribute__((ext_vector_type(8)));
typedef float  f32x4  __attribute__((ext_vector_type(4)));

#define RD_ 64

// ---------------------------------------------------------------- fp32 -> bf16 convert
__global__ __launch_bounds__(256) void cvt_f32_bf16(const float* __restrict__ in,
                                                    bf16_t* __restrict__ out) {
  int i = (blockIdx.x * 256 + threadIdx.x) * 4;
  float4 v = *(const float4*)&in[i];
  bf16x4 w;
  w[0] = (bf16_t)v.x; w[1] = (bf16_t)v.y; w[2] = (bf16_t)v.z; w[3] = (bf16_t)v.w;
  *(bf16x4*)&out[i] = w;
}

// ---------------------------------------------------------------- transpose + convert
// out[c][r] = (bf16)in[r][c];  in fp32 R x C, out bf16 C x R; R,C multiples of 32
__global__ __launch_bounds__(256) void transpose_cvt(const float* __restrict__ in,
                                                     bf16_t* __restrict__ out,
                                                     int R, int C) {
  __shared__ bf16_t t[32][33];
  int tx = threadIdx.x & 31, ty = threadIdx.x >> 5;
  int c0 = blockIdx.x * 32, r0 = blockIdx.y * 32;
#pragma unroll
  for (int i = 0; i < 4; i++)
    t[ty + 8 * i][tx] = (bf16_t)in[(size_t)(r0 + ty + 8 * i) * C + c0 + tx];
  __syncthreads();
#pragma unroll
  for (int i = 0; i < 4; i++)
    out[(size_t)(c0 + ty + 8 * i) * R + r0 + tx] = t[tx][ty + 8 * i];
}

// ---------------------------------------------------------------- MFMA GEMM
// C[m][n] = sum_k A[m][k] * Bt[n][k].  A: MxK bf16 row-major, Bt: NxK bf16 row-major.
// OutT = bf16 or float.
#define GM 128
#define GN 128
#define GK 32
#define LP 40   // LDS row pitch in bf16 (32 + 8 pad, keeps 16B alignment)

template <typename OutT>
__global__ __launch_bounds__(256) void gemm_bt(const bf16_t* __restrict__ A,
                                               const bf16_t* __restrict__ Bt,
                                               OutT* __restrict__ C,
                                               int M, int N, int K) {
  __shared__ bf16_t As[GM * LP];
  __shared__ bf16_t Bs[GN * LP];
  int tid  = threadIdx.x;
  int lane = tid & 63, wave = tid >> 6;
  int wm = (wave & 1) * 64, wn = (wave >> 1) * 64;
  int bm = blockIdx.x * GM, bn = blockIdx.y * GN;
  int qd = lane >> 4, lr = lane & 15;

  f32x4 acc[4][4] = {};

  int arow = tid >> 2;            // 0..63
  int akc  = (tid & 3) * 8;       // 0,8,16,24

  for (int k0 = 0; k0 < K; k0 += GK) {
    __syncthreads();
    *(bf16x8*)&As[arow * LP + akc]        = *(const bf16x8*)&A[(size_t)(bm + arow) * K + k0 + akc];
    *(bf16x8*)&As[(arow + 64) * LP + akc] = *(const bf16x8*)&A[(size_t)(bm + arow + 64) * K + k0 + akc];
    *(bf16x8*)&Bs[arow * LP + akc]        = *(const bf16x8*)&Bt[(size_t)(bn + arow) * K + k0 + akc];
    *(bf16x8*)&Bs[(arow + 64) * LP + akc] = *(const bf16x8*)&Bt[(size_t)(bn + arow + 64) * K + k0 + akc];
    __syncthreads();

    bf16x8 af[4], bfr[4];
#pragma unroll
    for (int t = 0; t < 4; t++) {
      af[t]  = *(const bf16x8*)&As[(wm + t * 16 + lr) * LP + qd * 8];
      bfr[t] = *(const bf16x8*)&Bs[(wn + t * 16 + lr) * LP + qd * 8];
    }
#pragma unroll
    for (int mt = 0; mt < 4; mt++)
#pragma unroll
      for (int nt = 0; nt < 4; nt++)
        acc[mt][nt] = __builtin_amdgcn_mfma_f32_16x16x32_bf16(af[mt], bfr[nt], acc[mt][nt], 0, 0, 0);
  }

#pragma unroll
  for (int mt = 0; mt < 4; mt++) {
    int rb = bm + wm + mt * 16 + qd * 4;
#pragma unroll
    for (int nt = 0; nt < 4; nt++) {
      int cc = bn + wn + nt * 16 + lr;
#pragma unroll
      for (int r = 0; r < 4; r++)
        C[(size_t)(rb + r) * N + cc] = (OutT)acc[mt][nt][r];
    }
  }
}

// ---------------------------------------------------------------- RMSNorm + partial RoPE
// One wave per (l, head) row; row length 256 bf16 (4 per lane). In-place safe.
template <int NHEADS, int HSTRIDE>
__global__ __launch_bounds__(256) void norm_rope(const bf16_t* __restrict__ in,
                                                 bf16_t* __restrict__ out,
                                                 const float* __restrict__ cosv,
                                                 const float* __restrict__ sinv,
                                                 const float* __restrict__ gamma) {
  int lane = threadIdx.x & 63;
  int idx  = blockIdx.x * 4 + (threadIdx.x >> 6);
  int l = idx / NHEADS, h = idx % NHEADS;
  size_t base = (size_t)l * NHEADS * HSTRIDE + (size_t)h * HSTRIDE;
  int d0 = lane * 4;

  bf16x4 raw = *(const bf16x4*)&in[base + d0];
  float x[4];
#pragma unroll
  for (int i = 0; i < 4; i++) x[i] = (float)raw[i];
  float ss = x[0] * x[0] + x[1] * x[1] + x[2] * x[2] + x[3] * x[3];
#pragma unroll
  for (int off = 32; off >= 1; off >>= 1) ss += __shfl_xor(ss, off);
  float inv = 1.0f / sqrtf(ss * (1.0f / 256.0f) + 1e-6f);

  float4 gr = *(const float4*)&gamma[d0];
  float n[4];
#pragma unroll
  for (int i = 0; i < 4; i++) n[i] = x[i] * inv * ((const float*)&gr)[i];

  // RoPE on dims [0,64): partner lives 32 dims = 8 lanes away
  float p[4];
#pragma unroll
  for (int i = 0; i < 4; i++) p[i] = __shfl_xor(n[i], 8);
  float o[4];
#pragma unroll
  for (int i = 0; i < 4; i++) o[i] = n[i];
  if (lane < 16) {
    float4 cr = *(const float4*)&cosv[(size_t)l * RD_ + d0];
    float4 sr = *(const float4*)&sinv[(size_t)l * RD_ + d0];
#pragma unroll
    for (int i = 0; i < 4; i++) {
      float rh = (lane < 8) ? -p[i] : p[i];   // rotate_half: [-x2, x1]
      o[i] = n[i] * ((const float*)&cr)[i] + rh * ((const float*)&sr)[i];
    }
  }
  bf16x4 w;
#pragma unroll
  for (int i = 0; i < 4; i++) w[i] = (bf16_t)o[i];
  *(bf16x4*)&out[base + d0] = w;
}

// ---------------------------------------------------------------- attention
// Grid: (L/16, 8). Block 256 = 4 waves; wave handles 4 consecutive q rows.
// qraw: L x 4096 bf16 (h*512+[0,256)=q normed+roped, +[256,512)=gate)
// kn/vb: L x 512 bf16; outg: L x 2048 bf16
#define ATJ 32
__global__ __launch_bounds__(256) void attn_kernel(const bf16_t* __restrict__ qraw,
                                                   const bf16_t* __restrict__ kn,
                                                   const bf16_t* __restrict__ vb,
                                                   bf16_t* __restrict__ outg) {
  __shared__ bf16_t ks[ATJ * 256];
  __shared__ bf16_t vs[ATJ * 256];
  int tid = threadIdx.x, lane = tid & 63, wave = tid >> 6;
  int qb = blockIdx.x, h = blockIdx.y, g = h >> 2;
  int i0 = qb * 16 + wave * 4;
  int d0 = lane * 4;

  float qv[4][4];
#pragma unroll
  for (int r = 0; r < 4; r++) {
    bf16x4 qq = *(const bf16x4*)&qraw[(size_t)(i0 + r) * 4096 + h * 512 + d0];
#pragma unroll
    for (int i = 0; i < 4; i++) qv[r][i] = (float)qq[i];
  }
  float o[4][4] = {};
  float mr[4], ls[4];
#pragma unroll
  for (int r = 0; r < 4; r++) { mr[r] = -1e30f; ls[r] = 0.0f; }

  int jmax = qb * 16 + 15;
  int ntiles = jmax / ATJ + 1;

  for (int jt = 0; jt < ntiles; jt++) {
    __syncthreads();
#pragma unroll
    for (int s = 0; s < 4; s++) {
      int c = tid + s * 256;                 // 0..1023
      int row = c >> 5, col = (c & 31) * 8;  // 32 rows x 256 cols
      size_t src = (size_t)(jt * ATJ + row) * 512 + g * 256 + col;
      *(bf16x8*)&ks[row * 256 + col] = *(const bf16x8*)&kn[src];
      *(bf16x8*)&vs[row * 256 + col] = *(const bf16x8*)&vb[src];
    }
    __syncthreads();

    int jlim = min(ATJ, jmax - jt * ATJ + 1);
    for (int j = 0; j < jlim; j++) {
      int jj = jt * ATJ + j;
      bf16x4 kq = *(const bf16x4*)&ks[j * 256 + d0];
      bf16x4 vq = *(const bf16x4*)&vs[j * 256 + d0];
      float kk[4], vvv[4];
#pragma unroll
      for (int i = 0; i < 4; i++) { kk[i] = (float)kq[i]; vvv[i] = (float)vq[i]; }
#pragma unroll
      for (int r = 0; r < 4; r++) {
        if (jj <= i0 + r) {   // wave-uniform predicate
          float s = qv[r][0] * kk[0] + qv[r][1] * kk[1] + qv[r][2] * kk[2] + qv[r][3] * kk[3];
          s += __shfl_xor(s, 32); s += __shfl_xor(s, 16); s += __shfl_xor(s, 8);
          s += __shfl_xor(s, 4);  s += __shfl_xor(s, 2);  s += __shfl_xor(s, 1);
          s *= 0.0625f;  // HEAD_DIM^-0.5
          float mnew  = fmaxf(mr[r], s);
          float alpha = __expf(mr[r] - mnew);
          float pe    = __expf(s - mnew);
          ls[r] = ls[r] * alpha + pe;
          mr[r] = mnew;
#pragma unroll
          for (int i = 0; i < 4; i++) o[r][i] = o[r][i] * alpha + pe * vvv[i];
        }
      }
    }
  }

#pragma unroll
  for (int r = 0; r < 4; r++) {
    int row = i0 + r;
    float inv = 1.0f / ls[r];
    bf16x4 gq = *(const bf16x4*)&qraw[(size_t)row * 4096 + h * 512 + 256 + d0];
    bf16x4 w;
#pragma unroll
    for (int i = 0; i < 4; i++) {
      float gt = (float)gq[i];
      float sg = 1.0f / (1.0f + __expf(-gt));
      w[i] = (bf16_t)(o[r][i] * inv * sg);
    }
    *(bf16x4*)&outg[(size_t)row * 2048 + h * 256 + d0] = w;
  }
}

// ---------------------------------------------------------------- launch
extern "C" void kernel_launch(void* const* d_in, const int* in_sizes, int n_in,
                              void* d_out, int out_size, void* d_ws, size_t ws_size,
                              hipStream_t stream) {
  const float* x    = (const float*)d_in[0];
  const float* cosv = (const float*)d_in[1];
  const float* sinv = (const float*)d_in[2];
  // d_in[3] = mask (causal triu k=1) — deterministic, hardcoded in attn_kernel
  const float* wq   = (const float*)d_in[4];
  const float* wk   = (const float*)d_in[5];
  const float* wv   = (const float*)d_in[6];
  const float* wo   = (const float*)d_in[7];
  const float* qg   = (const float*)d_in[8];
  const float* kg   = (const float*)d_in[9];
  float* outp = (float*)d_out;   // OUTPUT IS FP32 (R4 diagnosis)

  char* ws = (char*)d_ws;
  size_t off = 0;
  auto alloc = [&](size_t bytes) { char* p = ws + off; off += (bytes + 255) & ~255ull; return p; };

  bf16_t* x_bf  = (bf16_t*)alloc((size_t)4096 * 2048 * 2);  // 16 MB
  bf16_t* wqT   = (bf16_t*)alloc((size_t)2048 * 4096 * 2);  // 16 MB  (4096 x 2048)
  bf16_t* wkT   = (bf16_t*)alloc((size_t)2048 * 512 * 2);   //  2 MB  (512 x 2048)
  bf16_t* wvT   = (bf16_t*)alloc((size_t)2048 * 512 * 2);   //  2 MB
  bf16_t* woT   = (bf16_t*)alloc((size_t)2048 * 2048 * 2);  //  8 MB  (2048 x 2048)
  bf16_t* q_raw = (bf16_t*)alloc((size_t)4096 * 4096 * 2);  // 32 MB  (L x 4096)
  bf16_t* k_raw = (bf16_t*)alloc((size_t)4096 * 512 * 2);   //  4 MB
  bf16_t* v_b   = (bf16_t*)alloc((size_t)4096 * 512 * 2);   //  4 MB
  bf16_t* attn_g= (bf16_t*)alloc((size_t)4096 * 2048 * 2);  // 16 MB
  // total ~100 MB of ws

  dim3 blk(256);
  // x fp32 -> bf16
  cvt_f32_bf16<<<8192, blk, 0, stream>>>(x, x_bf);

  // weight transposes (+convert): grid (C/32, R/32) for in R x C
  transpose_cvt<<<dim3(4096 / 32, 2048 / 32), blk, 0, stream>>>(wq, wqT, 2048, 4096);
  transpose_cvt<<<dim3(512 / 32, 2048 / 32), blk, 0, stream>>>(wk, wkT, 2048, 512);
  transpose_cvt<<<dim3(512 / 32, 2048 / 32), blk, 0, stream>>>(wv, wvT, 2048, 512);
  transpose_cvt<<<dim3(2048 / 32, 2048 / 32), blk, 0, stream>>>(wo, woT, 2048, 2048);

  // projections (bf16 MFMA)
  gemm_bt<bf16_t><<<dim3(4096 / 128, 4096 / 128), blk, 0, stream>>>(x_bf, wqT, q_raw, 4096, 4096, 2048);
  gemm_bt<bf16_t><<<dim3(4096 / 128, 512 / 128), blk, 0, stream>>>(x_bf, wkT, k_raw, 4096, 512, 2048);
  gemm_bt<bf16_t><<<dim3(4096 / 128, 512 / 128), blk, 0, stream>>>(x_bf, wvT, v_b, 4096, 512, 2048);

  // QK norm + partial RoPE (in-place for q)
  norm_rope<8, 512><<<4096 * 8 / 4, blk, 0, stream>>>(q_raw, q_raw, cosv, sinv, qg);
  norm_rope<2, 256><<<4096 * 2 / 4, blk, 0, stream>>>(k_raw, k_raw, cosv, sinv, kg);

  // causal GQA attention + sigmoid gate (bf16 out)
  attn_kernel<<<dim3(4096 / 16, 8), blk, 0, stream>>>(q_raw, k_raw, v_b, attn_g);

  // output projection -> FP32 final output
  gemm_bt<float><<<dim3(4096 / 128, 2048 / 128), blk, 0, stream>>>(attn_g, woT, outp, 4096, 2048, 2048);
}

// Round 6
// 785.261 us; speedup vs baseline: 12.7386x; 12.7386x over previous
//
#include <hip/hip_runtime.h>
#include <hip/hip_bf16.h>
#include <math.h>

typedef __bf16 bf16_t;
typedef __bf16 bf16x4 __attribute__((ext_vector_type(4)));
typedef __bf16 bf16x8 __attribute__((ext_vector_type(8)));
typedef float  f32x4  __attribute__((ext_vector_type(4)));

#define RD_ 64

// ---------------------------------------------------------------- fp32 -> bf16 convert
__global__ __launch_bounds__(256) void cvt_f32_bf16(const float* __restrict__ in,
                                                    bf16_t* __restrict__ out) {
  int i = (blockIdx.x * 256 + threadIdx.x) * 4;
  float4 v = *(const float4*)&in[i];
  bf16x4 w;
  w[0] = (bf16_t)v.x; w[1] = (bf16_t)v.y; w[2] = (bf16_t)v.z; w[3] = (bf16_t)v.w;
  *(bf16x4*)&out[i] = w;
}

// ---------------------------------------------------------------- transpose + convert (fp32 in)
__global__ __launch_bounds__(256) void transpose_cvt(const float* __restrict__ in,
                                                     bf16_t* __restrict__ out,
                                                     int R, int C) {
  __shared__ bf16_t t[32][33];
  int tx = threadIdx.x & 31, ty = threadIdx.x >> 5;
  int c0 = blockIdx.x * 32, r0 = blockIdx.y * 32;
#pragma unroll
  for (int i = 0; i < 4; i++)
    t[ty + 8 * i][tx] = (bf16_t)in[(size_t)(r0 + ty + 8 * i) * C + c0 + tx];
  __syncthreads();
#pragma unroll
  for (int i = 0; i < 4; i++)
    out[(size_t)(c0 + ty + 8 * i) * R + r0 + tx] = t[tx][ty + 8 * i];
}

// ---------------------------------------------------------------- bf16 transpose (for V^T)
__global__ __launch_bounds__(256) void transpose_bf16(const bf16_t* __restrict__ in,
                                                      bf16_t* __restrict__ out,
                                                      int R, int C) {
  __shared__ bf16_t t[32][33];
  int tx = threadIdx.x & 31, ty = threadIdx.x >> 5;
  int c0 = blockIdx.x * 32, r0 = blockIdx.y * 32;
#pragma unroll
  for (int i = 0; i < 4; i++)
    t[ty + 8 * i][tx] = in[(size_t)(r0 + ty + 8 * i) * C + c0 + tx];
  __syncthreads();
#pragma unroll
  for (int i = 0; i < 4; i++)
    out[(size_t)(c0 + ty + 8 * i) * R + r0 + tx] = t[tx][ty + 8 * i];
}

// ---------------------------------------------------------------- MFMA GEMM
// C[m][n] = sum_k A[m][k] * Bt[n][k].  A: MxK bf16, Bt: NxK bf16. OutT = bf16 or float.
#define GM 128
#define GN 128
#define GK 32
#define LP 40

template <typename OutT>
__global__ __launch_bounds__(256) void gemm_bt(const bf16_t* __restrict__ A,
                                               const bf16_t* __restrict__ Bt,
                                               OutT* __restrict__ C,
                                               int M, int N, int K) {
  __shared__ bf16_t As[GM * LP];
  __shared__ bf16_t Bs[GN * LP];
  int tid  = threadIdx.x;
  int lane = tid & 63, wave = tid >> 6;
  int wm = (wave & 1) * 64, wn = (wave >> 1) * 64;
  int bm = blockIdx.x * GM, bn = blockIdx.y * GN;
  int qd = lane >> 4, lr = lane & 15;

  f32x4 acc[4][4] = {};

  int arow = tid >> 2;
  int akc  = (tid & 3) * 8;

  for (int k0 = 0; k0 < K; k0 += GK) {
    __syncthreads();
    *(bf16x8*)&As[arow * LP + akc]        = *(const bf16x8*)&A[(size_t)(bm + arow) * K + k0 + akc];
    *(bf16x8*)&As[(arow + 64) * LP + akc] = *(const bf16x8*)&A[(size_t)(bm + arow + 64) * K + k0 + akc];
    *(bf16x8*)&Bs[arow * LP + akc]        = *(const bf16x8*)&Bt[(size_t)(bn + arow) * K + k0 + akc];
    *(bf16x8*)&Bs[(arow + 64) * LP + akc] = *(const bf16x8*)&Bt[(size_t)(bn + arow + 64) * K + k0 + akc];
    __syncthreads();

    bf16x8 af[4], bfr[4];
#pragma unroll
    for (int t = 0; t < 4; t++) {
      af[t]  = *(const bf16x8*)&As[(wm + t * 16 + lr) * LP + qd * 8];
      bfr[t] = *(const bf16x8*)&Bs[(wn + t * 16 + lr) * LP + qd * 8];
    }
#pragma unroll
    for (int mt = 0; mt < 4; mt++)
#pragma unroll
      for (int nt = 0; nt < 4; nt++)
        acc[mt][nt] = __builtin_amdgcn_mfma_f32_16x16x32_bf16(af[mt], bfr[nt], acc[mt][nt], 0, 0, 0);
  }

#pragma unroll
  for (int mt = 0; mt < 4; mt++) {
    int rb = bm + wm + mt * 16 + qd * 4;
#pragma unroll
    for (int nt = 0; nt < 4; nt++) {
      int cc = bn + wn + nt * 16 + lr;
#pragma unroll
      for (int r = 0; r < 4; r++)
        C[(size_t)(rb + r) * N + cc] = (OutT)acc[mt][nt][r];
    }
  }
}

// ---------------------------------------------------------------- RMSNorm + partial RoPE
template <int NHEADS, int HSTRIDE>
__global__ __launch_bounds__(256) void norm_rope(const bf16_t* __restrict__ in,
                                                 bf16_t* __restrict__ out,
                                                 const float* __restrict__ cosv,
                                                 const float* __restrict__ sinv,
                                                 const float* __restrict__ gamma) {
  int lane = threadIdx.x & 63;
  int idx  = blockIdx.x * 4 + (threadIdx.x >> 6);
  int l = idx / NHEADS, h = idx % NHEADS;
  size_t base = (size_t)l * NHEADS * HSTRIDE + (size_t)h * HSTRIDE;
  int d0 = lane * 4;

  bf16x4 raw = *(const bf16x4*)&in[base + d0];
  float x[4];
#pragma unroll
  for (int i = 0; i < 4; i++) x[i] = (float)raw[i];
  float ss = x[0] * x[0] + x[1] * x[1] + x[2] * x[2] + x[3] * x[3];
#pragma unroll
  for (int off = 32; off >= 1; off >>= 1) ss += __shfl_xor(ss, off);
  float inv = 1.0f / sqrtf(ss * (1.0f / 256.0f) + 1e-6f);

  float4 gr = *(const float4*)&gamma[d0];
  float n[4];
#pragma unroll
  for (int i = 0; i < 4; i++) n[i] = x[i] * inv * ((const float*)&gr)[i];

  float p[4];
#pragma unroll
  for (int i = 0; i < 4; i++) p[i] = __shfl_xor(n[i], 8);
  float o[4];
#pragma unroll
  for (int i = 0; i < 4; i++) o[i] = n[i];
  if (lane < 16) {
    float4 cr = *(const float4*)&cosv[(size_t)l * RD_ + d0];
    float4 sr = *(const float4*)&sinv[(size_t)l * RD_ + d0];
#pragma unroll
    for (int i = 0; i < 4; i++) {
      float rh = (lane < 8) ? -p[i] : p[i];
      o[i] = n[i] * ((const float*)&cr)[i] + rh * ((const float*)&sr)[i];
    }
  }
  bf16x4 w;
#pragma unroll
  for (int i = 0; i < 4; i++) w[i] = (bf16_t)o[i];
  *(bf16x4*)&out[base + d0] = w;
}

// ---------------------------------------------------------------- MFMA flash attention
// Grid (64, 8). Block = 4 waves; wave w handles 16 q-rows [qb*64+w*16, +16).
// qraw: L x 4096 bf16 (h*512: q | +256: gate); kn: L x 512 bf16 (roped K);
// vt: [512][4096] bf16 = V^T per d_global=g*256+d; outg: L x 2048 bf16.
#define JT 32
#define KSP 264   // ks row pitch (bf16): 2-way bank aliasing, 16B-aligned rows
#define VSP 56    // vst row pitch
#define PSP 40    // ps row pitch

__global__ __launch_bounds__(256) void attn_mfma(const bf16_t* __restrict__ qraw,
                                                 const bf16_t* __restrict__ kn,
                                                 const bf16_t* __restrict__ vt,
                                                 bf16_t* __restrict__ outg) {
  __shared__ __align__(16) bf16_t ks[JT * KSP];     // [j][d]   16.9 KB
  __shared__ __align__(16) bf16_t vst[256 * VSP];   // [d][j]   28.7 KB
  __shared__ __align__(16) bf16_t ps[4][16 * PSP];  // per-wave P [m][j]  5 KB
  int tid = threadIdx.x, lane = tid & 63, wave = tid >> 6;
  int qb = (int)gridDim.x - 1 - (int)blockIdx.x;    // heavy blocks first
  int h = blockIdx.y, g = h >> 2;
  int iw = qb * 64 + wave * 16;
  int m = lane & 15, quad = lane >> 4;

  // Q fragments: A-layout, 8 k-chunks of 32 over d=256
  bf16x8 qf[8];
  const bf16_t* qbase = qraw + (size_t)(iw + m) * 4096 + h * 512;
#pragma unroll
  for (int kc = 0; kc < 8; kc++)
    qf[kc] = *(const bf16x8*)(qbase + kc * 32 + quad * 8);

  f32x4 o[16] = {};
  float mr[4], ls[4];
#pragma unroll
  for (int r = 0; r < 4; r++) { mr[r] = -1e30f; ls[r] = 0.0f; }

  int ntiles = qb * 2 + 2;
  for (int jt = 0; jt < ntiles; jt++) {
    int j0 = jt * JT;
    __syncthreads();
    // stage K tile: 32 rows x 256 d  (1024 slots of 8 bf16)
#pragma unroll
    for (int s = 0; s < 4; s++) {
      int slot = tid + s * 256;
      int row = slot >> 5, ch = slot & 31;
      *(bf16x8*)&ks[row * KSP + ch * 8] =
          *(const bf16x8*)&kn[(size_t)(j0 + row) * 512 + g * 256 + ch * 8];
    }
    // stage V^T tile: 256 d x 32 j (1024 slots of 8 bf16)
#pragma unroll
    for (int s = 0; s < 4; s++) {
      int slot = tid + s * 256;
      int d = slot >> 2, jc = slot & 3;
      *(bf16x8*)&vst[d * VSP + jc * 8] =
          *(const bf16x8*)&vt[(size_t)(g * 256 + d) * 4096 + j0 + jc * 8];
    }
    __syncthreads();

    if (j0 > iw + 15) continue;   // fully masked for this wave's rows

    // ---- S = Q K^T : 2 n-tiles of 16 cols ----
    f32x4 sacc[2] = {};
#pragma unroll
    for (int nt = 0; nt < 2; nt++)
#pragma unroll
      for (int kc = 0; kc < 8; kc++) {
        bf16x8 kf = *(const bf16x8*)&ks[(nt * 16 + m) * KSP + kc * 32 + quad * 8];
        sacc[nt] = __builtin_amdgcn_mfma_f32_16x16x32_bf16(qf[kc], kf, sacc[nt], 0, 0, 0);
      }

    float s[2][4];
    bool diag = (j0 + JT - 1 > iw);   // tile overlaps causal diagonal
#pragma unroll
    for (int nt = 0; nt < 2; nt++)
#pragma unroll
      for (int r = 0; r < 4; r++) {
        float v = sacc[nt][r] * 0.0625f;
        if (diag) {
          int jj = j0 + nt * 16 + m;
          int ii = iw + quad * 4 + r;
          if (jj > ii) v = -1e30f;
        }
        s[nt][r] = v;
      }

    // ---- online softmax: row reductions across the 16 lanes of each quad ----
    float mt[4], alpha[4], p0[4], p1[4], rs[4];
#pragma unroll
    for (int r = 0; r < 4; r++) mt[r] = fmaxf(s[0][r], s[1][r]);
#pragma unroll
    for (int off = 8; off >= 1; off >>= 1)
#pragma unroll
      for (int r = 0; r < 4; r++) mt[r] = fmaxf(mt[r], __shfl_xor(mt[r], off));
#pragma unroll
    for (int r = 0; r < 4; r++) {
      float mn = fmaxf(mr[r], mt[r]);
      alpha[r] = __expf(mr[r] - mn);
      mr[r] = mn;
      p0[r] = __expf(s[0][r] - mn);
      p1[r] = __expf(s[1][r] - mn);
      rs[r] = p0[r] + p1[r];
    }
#pragma unroll
    for (int off = 8; off >= 1; off >>= 1)
#pragma unroll
      for (int r = 0; r < 4; r++) rs[r] += __shfl_xor(rs[r], off);
#pragma unroll
    for (int r = 0; r < 4; r++) ls[r] = ls[r] * alpha[r] + rs[r];

    // ---- P: C-layout -> A-layout via per-wave LDS ----
    bf16_t* pw = &ps[wave][0];
#pragma unroll
    for (int r = 0; r < 4; r++) {
      pw[(quad * 4 + r) * PSP + m]      = (bf16_t)p0[r];
      pw[(quad * 4 + r) * PSP + 16 + m] = (bf16_t)p1[r];
    }
    __asm__ volatile("s_waitcnt lgkmcnt(0)" ::: "memory");
    bf16x8 pf = *(const bf16x8*)&pw[m * PSP + quad * 8];

    // ---- O rescale + PV ----
#pragma unroll
    for (int dt = 0; dt < 16; dt++)
#pragma unroll
      for (int r = 0; r < 4; r++) o[dt][r] *= alpha[r];
#pragma unroll
    for (int dt = 0; dt < 16; dt++) {
      bf16x8 vf = *(const bf16x8*)&vst[(dt * 16 + m) * VSP + quad * 8];
      o[dt] = __builtin_amdgcn_mfma_f32_16x16x32_bf16(pf, vf, o[dt], 0, 0, 0);
    }
  }

  // ---- epilogue: 1/l, sigmoid gate, store ----
  float linv[4];
#pragma unroll
  for (int r = 0; r < 4; r++) linv[r] = 1.0f / ls[r];
  const bf16_t* gbase = qraw + (size_t)iw * 4096 + h * 512 + 256;
#pragma unroll
  for (int dt = 0; dt < 16; dt++) {
    int d = dt * 16 + m;
#pragma unroll
    for (int r = 0; r < 4; r++) {
      int row = quad * 4 + r;
      float gt = (float)gbase[(size_t)row * 4096 + d];
      float sg = 1.0f / (1.0f + __expf(-gt));
      outg[(size_t)(iw + row) * 2048 + h * 256 + d] = (bf16_t)(o[dt][r] * linv[r] * sg);
    }
  }
}

// ---------------------------------------------------------------- launch
extern "C" void kernel_launch(void* const* d_in, const int* in_sizes, int n_in,
                              void* d_out, int out_size, void* d_ws, size_t ws_size,
                              hipStream_t stream) {
  const float* x    = (const float*)d_in[0];
  const float* cosv = (const float*)d_in[1];
  const float* sinv = (const float*)d_in[2];
  // d_in[3] = mask (causal triu k=1) — deterministic, hardcoded
  const float* wq   = (const float*)d_in[4];
  const float* wk   = (const float*)d_in[5];
  const float* wv   = (const float*)d_in[6];
  const float* wo   = (const float*)d_in[7];
  const float* qg   = (const float*)d_in[8];
  const float* kg   = (const float*)d_in[9];
  float* outp = (float*)d_out;   // output is fp32

  char* ws = (char*)d_ws;
  size_t off = 0;
  auto alloc = [&](size_t bytes) { char* p = ws + off; off += (bytes + 255) & ~255ull; return p; };

  bf16_t* x_bf  = (bf16_t*)alloc((size_t)4096 * 2048 * 2);  // 16 MB
  bf16_t* wqT   = (bf16_t*)alloc((size_t)2048 * 4096 * 2);  // 16 MB
  bf16_t* wkT   = (bf16_t*)alloc((size_t)2048 * 512 * 2);   //  2 MB
  bf16_t* wvT   = (bf16_t*)alloc((size_t)2048 * 512 * 2);   //  2 MB
  bf16_t* woT   = (bf16_t*)alloc((size_t)2048 * 2048 * 2);  //  8 MB
  bf16_t* q_raw = (bf16_t*)alloc((size_t)4096 * 4096 * 2);  // 32 MB
  bf16_t* k_raw = (bf16_t*)alloc((size_t)4096 * 512 * 2);   //  4 MB
  bf16_t* v_b   = (bf16_t*)alloc((size_t)4096 * 512 * 2);   //  4 MB
  bf16_t* v_t   = (bf16_t*)alloc((size_t)512 * 4096 * 2);   //  4 MB (V^T)
  bf16_t* attn_g= (bf16_t*)alloc((size_t)4096 * 2048 * 2);  // 16 MB

  dim3 blk(256);
  cvt_f32_bf16<<<8192, blk, 0, stream>>>(x, x_bf);

  transpose_cvt<<<dim3(4096 / 32, 2048 / 32), blk, 0, stream>>>(wq, wqT, 2048, 4096);
  transpose_cvt<<<dim3(512 / 32, 2048 / 32), blk, 0, stream>>>(wk, wkT, 2048, 512);
  transpose_cvt<<<dim3(512 / 32, 2048 / 32), blk, 0, stream>>>(wv, wvT, 2048, 512);
  transpose_cvt<<<dim3(2048 / 32, 2048 / 32), blk, 0, stream>>>(wo, woT, 2048, 2048);

  gemm_bt<bf16_t><<<dim3(4096 / 128, 4096 / 128), blk, 0, stream>>>(x_bf, wqT, q_raw, 4096, 4096, 2048);
  gemm_bt<bf16_t><<<dim3(4096 / 128, 512 / 128), blk, 0, stream>>>(x_bf, wkT, k_raw, 4096, 512, 2048);
  gemm_bt<bf16_t><<<dim3(4096 / 128, 512 / 128), blk, 0, stream>>>(x_bf, wvT, v_b, 4096, 512, 2048);

  norm_rope<8, 512><<<4096 * 8 / 4, blk, 0, stream>>>(q_raw, q_raw, cosv, sinv, qg);
  norm_rope<2, 256><<<4096 * 2 / 4, blk, 0, stream>>>(k_raw, k_raw, cosv, sinv, kg);

  // V^T for the PV MFMA B-operand
  transpose_bf16<<<dim3(512 / 32, 4096 / 32), blk, 0, stream>>>(v_b, v_t, 4096, 512);

  attn_mfma<<<dim3(64, 8), blk, 0, stream>>>(q_raw, k_raw, v_t, attn_g);

  gemm_bt<float><<<dim3(4096 / 128, 2048 / 128), blk, 0, stream>>>(attn_g, woT, outp, 4096, 2048, 2048);
}